// Round 10
// baseline (165.591 us; speedup 1.0000x reference)
//
#include <hip/hip_runtime.h>
#include <hip/hip_bf16.h>
#include <cmath>

#define BB 4
#define NN 2048
#define DIN 128
#define HH 4
#define HD 32
#define KSEL 204            // int(0.1 * 2048)
#define BH (BB*HH)
#define KPAD 256            // K padded to 8 MFMA steps of 32
#define KST 264             // PSb row stride (shorts): 132 words -> 2-way banks (free)

typedef __attribute__((ext_vector_type(8))) short short8;
typedef __attribute__((ext_vector_type(4))) short short4v;
typedef __attribute__((ext_vector_type(4))) float float4v;

static __device__ inline short f2bf(float x) {
    __hip_bfloat16 b = __float2bfloat16(x);   // RNE
    return __builtin_bit_cast(short, b);
}

// ---------------------------------------------------------------------------
// K1: MEGA-select per (b,h), 1024 threads (16 waves).
//  Phase A: s_i/s_j dots (f32-exact) for rows 2t,2t+1 (si -> global, sj local)
//  Phase B: radix-select top-KSEL on register keys, parallel suffix-scan
//  Phase C: ordered compaction -> idxsel/sjsel/idxLDS
//  Phase D: Whsel[bh][d][jj] = bf16( h[sel jj] @ W[hh] ) via MFMA, zero tail.
// Replaces old hcvt+s+wh+select (Wh only ever needed for the 204 selected rows).
__global__ __launch_bounds__(1024) void select_kernel(
        const float* __restrict__ h, const float* __restrict__ W,
        const float* __restrict__ a, float* __restrict__ si,
        int* __restrict__ idxsel, float* __restrict__ sjsel,
        float* __restrict__ sjmax, short* __restrict__ Whsel) {
    int bh = blockIdx.x;
    int b = bh >> 2, hh = bh & 3;
    int t = threadIdx.x, lane = t & 63, w = t >> 6;
    __shared__ float sv[NN];                 // s_j values
    __shared__ float w1[128], w2[128];       // W@a halves
    __shared__ short WT[32][136];            // WT[d][k] = bf16(W[hh][k][d])
    __shared__ int hist16[16][256];
    __shared__ int binInfo[2];               // [0]=Bsel, [1]=cum_before
    __shared__ int wtot[4];
    __shared__ int wtotg[16], wtote[16], woffg[16], woffe[16];
    __shared__ float wmax[16];
    __shared__ int idxLDS[KSEL];

    // stage wa (threads 0..255) + WT (all threads)
    if (t < 256) {
        int f = t & 127, half = t >> 7;
        const float* Wp = W + (size_t)hh * (DIN * HD) + f * HD;
        const float* ap = a + hh * 64 + half * 32;
        float acc = 0.f;
#pragma unroll
        for (int d = 0; d < 32; ++d) acc += Wp[d] * ap[d];
        if (half == 0) w1[f] = acc; else w2[f] = acc;
    }
    for (int e = t; e < 32 * 128; e += 1024) {
        int n = e >> 7, k = e & 127;
        WT[n][k] = f2bf(W[(size_t)hh * (DIN * HD) + k * HD + n]);
    }
    __syncthreads();

    // Phase A: s-dots for rows j0, j0+1
    int j0 = t * 2;
    float s1a = 0.f, s2a = 0.f, s1b = 0.f, s2b = 0.f;
    {
        const float4* hr0 = (const float4*)(h + ((size_t)b * NN + j0) * DIN);
        const float4* hr1 = hr0 + (DIN / 4);
#pragma unroll 8
        for (int q = 0; q < 32; ++q) {
            float4 x = hr0[q];
            s1a += x.x * w1[q*4] + x.y * w1[q*4+1] + x.z * w1[q*4+2] + x.w * w1[q*4+3];
            s2a += x.x * w2[q*4] + x.y * w2[q*4+1] + x.z * w2[q*4+2] + x.w * w2[q*4+3];
            float4 y = hr1[q];
            s1b += y.x * w1[q*4] + y.y * w1[q*4+1] + y.z * w1[q*4+2] + y.w * w1[q*4+3];
            s2b += y.x * w2[q*4] + y.y * w2[q*4+1] + y.z * w2[q*4+2] + y.w * w2[q*4+3];
        }
    }
    si[(size_t)bh * NN + j0]     = s1a;
    si[(size_t)bh * NN + j0 + 1] = s1b;
    sv[j0] = s2a; sv[j0 + 1] = s2b;
    unsigned u0 = __builtin_bit_cast(unsigned, s2a);
    unsigned u1 = __builtin_bit_cast(unsigned, s2b);
    u0 = (u0 & 0x80000000u) ? ~u0 : (u0 | 0x80000000u);
    u1 = (u1 & 0x80000000u) ? ~u1 : (u1 | 0x80000000u);
    float lmax = fmaxf(s2a, s2b);
#pragma unroll
    for (int off = 32; off >= 1; off >>= 1) lmax = fmaxf(lmax, __shfl_xor(lmax, off));
    if (lane == 0) wmax[w] = lmax;
    __syncthreads();
    if (t == 0) {
        float m = wmax[0];
#pragma unroll
        for (int i = 1; i < 16; ++i) m = fmaxf(m, wmax[i]);
        sjmax[bh] = m;
    }

    // Phase B: radix
    unsigned prefix = 0;
    int need = KSEL;
#pragma unroll
    for (int shift = 24; shift >= 0; shift -= 8) {
        ((int*)hist16)[t] = 0; ((int*)hist16)[t + 1024] = 0;
        ((int*)hist16)[t + 2048] = 0; ((int*)hist16)[t + 3072] = 0;
        __syncthreads();
        unsigned hmask = (shift < 24) ? (0xFFFFFFFFu << (shift + 8)) : 0u;
        if (((u0 ^ prefix) & hmask) == 0) atomicAdd(&hist16[w][(u0 >> shift) & 255], 1);
        if (((u1 ^ prefix) & hmask) == 0) atomicAdd(&hist16[w][(u1 >> shift) & 255], 1);
        __syncthreads();
        int sc = 0, hv = 0, bb = 0;
        if (t < 256) {                 // waves 0..3
            bb = 255 - t;
            hv = 0;
#pragma unroll
            for (int i = 0; i < 16; ++i) hv += hist16[i][bb];
            sc = hv;
#pragma unroll
            for (int off = 1; off < 64; off <<= 1) {
                int u = __shfl_up(sc, off);
                if (lane >= off) sc += u;
            }
            if (lane == 63) wtot[w] = sc;
        }
        __syncthreads();
        if (t < 256) {
            int woffset = 0;
#pragma unroll
            for (int i = 0; i < 4; ++i) woffset += (i < w) ? wtot[i] : 0;
            int incl = sc + woffset;
            int excl = incl - hv;
            if (incl >= need && excl < need) {   // unique thread
                binInfo[0] = bb;
                binInfo[1] = excl;
            }
        }
        __syncthreads();
        prefix |= ((unsigned)binInfo[0]) << shift;
        need -= binInfo[1];
        __syncthreads();
    }
    unsigned T = prefix;
    int n_gt = KSEL - need;        // count of keys strictly > T

    // Phase C: ordered compaction (thread t owns j0, j0+1)
    int cg = (u0 > T ? 1 : 0) + (u1 > T ? 1 : 0);
    int ce = (u0 == T ? 1 : 0) + (u1 == T ? 1 : 0);
    int sg = cg, se = ce;
#pragma unroll
    for (int off = 1; off < 64; off <<= 1) {
        int ug = __shfl_up(sg, off), ue = __shfl_up(se, off);
        if (lane >= off) { sg += ug; se += ue; }
    }
    if (lane == 63) { wtotg[w] = sg; wtote[w] = se; }
    __syncthreads();
    if (t == 0) {
        int rg = 0, re = 0;
#pragma unroll
        for (int i = 0; i < 16; ++i) {
            woffg[i] = rg; rg += wtotg[i];
            woffe[i] = re; re += wtote[i];
        }
    }
    __syncthreads();
    int pg = woffg[w] + sg - cg;
    int te = woffe[w] + se - ce;
    {
        unsigned kk[2] = {u0, u1};
#pragma unroll
        for (int r = 0; r < 2; ++r) {
            int j = j0 + r;
            if (kk[r] > T) {
                idxsel[bh * KSEL + pg] = j;
                sjsel[bh * KSEL + pg] = sv[j];
                idxLDS[pg] = j;
                pg++;
            } else if (kk[r] == T) {
                if (te < need) {
                    int pos = n_gt + te;
                    idxsel[bh * KSEL + pos] = j;
                    sjsel[bh * KSEL + pos] = sv[j];
                    idxLDS[pos] = j;
                }
                te++;
            }
        }
    }
    __syncthreads();

    // Phase D: Whsel[bh][d][jj] = bf16( h[idxLDS[jj]] @ W[hh] ), tail zero.
    // wave w owns m-tile w (16 jj's); A-frag gathered+cvt from f32 h.
    {
        int mr = lane & 15, quad = lane >> 4;
        int jjp = w * 16 + mr;
        bool valid = jjp < KSEL;
        const float* hrow = h + ((size_t)b * NN + (valid ? idxLDS[jjp] : 0)) * DIN + quad * 8;
        float4v acc0 = {0.f, 0.f, 0.f, 0.f};
        float4v acc1 = {0.f, 0.f, 0.f, 0.f};
#pragma unroll
        for (int ks = 0; ks < 4; ++ks) {
            short8 afr;
            if (valid) {
                float4 xa = *(const float4*)(hrow + ks * 32);
                float4 xb = *(const float4*)(hrow + ks * 32 + 4);
                afr[0] = f2bf(xa.x); afr[1] = f2bf(xa.y); afr[2] = f2bf(xa.z); afr[3] = f2bf(xa.w);
                afr[4] = f2bf(xb.x); afr[5] = f2bf(xb.y); afr[6] = f2bf(xb.z); afr[7] = f2bf(xb.w);
            } else {
                afr = (short8){0, 0, 0, 0, 0, 0, 0, 0};
            }
            short8 b0 = *(const short8*)&WT[mr][ks * 32 + quad * 8];
            short8 b1 = *(const short8*)&WT[16 + mr][ks * 32 + quad * 8];
            acc0 = __builtin_amdgcn_mfma_f32_16x16x32_bf16(afr, b0, acc0, 0, 0, 0);
            acc1 = __builtin_amdgcn_mfma_f32_16x16x32_bf16(afr, b1, acc1, 0, 0, 0);
        }
        short4v o0, o1;
#pragma unroll
        for (int r = 0; r < 4; ++r) { o0[r] = f2bf(acc0[r]); o1[r] = f2bf(acc1[r]); }
        size_t base = (size_t)bh * HD * KPAD;
        int jjs = w * 16 + quad * 4;
        *(short4v*)&Whsel[base + (size_t)mr * KPAD + jjs] = o0;
        *(short4v*)&Whsel[base + (size_t)(16 + mr) * KPAD + jjs] = o1;
    }
}

// ---------------------------------------------------------------------------
// K2: FUSED attention. Block = (b, 16 rows, 4 heads-as-waves), grid 512.
// 4 stages: 4 dense adj rows -> LDS (shared by all heads); wave w computes
// head w's P rows into its PRIVATE PSb[w]; barriers only guard adjbuf.
// Then wave w MFMAs PSb[w] @ bfr (registers) -> out * invZ. ~75 KB LDS.
__global__ __launch_bounds__(256) void attn2_kernel(
        const float* __restrict__ adj, const float* __restrict__ si,
        const int* __restrict__ idxsel, const float* __restrict__ sjsel,
        const float* __restrict__ sjmax, const short* __restrict__ Whsel,
        float* __restrict__ out) {
    int b = blockIdx.x >> 7;        // 4
    int tile = blockIdx.x & 127;    // 128 tiles of 16 rows
    __shared__ float adjbuf[4][NN];          // 32 KB
    __shared__ short PSb[HH][16][KST];       // 33 KB, per-head private
    __shared__ int   idxS[HH][KPAD];         // 4 KB
    __shared__ float sjS[HH][KPAD];          // 4 KB
    __shared__ float invZS[HH][16];
    __shared__ float smaxS[HH];
    int t = threadIdx.x, w = t >> 6, lane = t & 63;
    int mr = lane & 15, quad = lane >> 4;

    // padded per-head tables
    for (int e = t; e < HH * KPAD; e += 256) {
        int hh = e >> 8, jj = e & 255;
        bool v = jj < KSEL;
        idxS[hh][jj] = v ? idxsel[(b * HH + hh) * KSEL + jj] : 0;
        sjS[hh][jj]  = v ? sjsel[(b * HH + hh) * KSEL + jj] : -1e30f;
    }
    if (t < HH) smaxS[t] = sjmax[b * HH + t];

    // B-fragments for head w (registers, reused all block)
    short8 bfr[2][8];
    {
        const short* wp = Whsel + (size_t)((b * HH + w) * HD) * KPAD;
#pragma unroll
        for (int ni = 0; ni < 2; ++ni)
#pragma unroll
            for (int ks = 0; ks < 8; ++ks)
                bfr[ni][ks] = *(const short8*)(wp + (size_t)(ni * 16 + mr) * KPAD + ks * 32 + quad * 8);
    }

    int i0 = tile * 16;
    const float* adjb = adj + (size_t)b * NN * NN;
    // stage 0: 4 dense adj rows
    {
        const float4* src = (const float4*)(adjb + (size_t)i0 * NN);
        float4* dst = (float4*)adjbuf;
#pragma unroll
        for (int q = 0; q < 8; ++q)
            dst[q * 256 + t] = src[q * 256 + t];
    }
    __syncthreads();

    int bh = b * HH + w;
    float smax = smaxS[w];
    for (int s = 0; s < 4; ++s) {
#pragma unroll
        for (int r = 0; r < 4; ++r) {
            int i_loc = s * 4 + r;
            int i = i0 + i_loc;
            float siv = si[(size_t)bh * NN + i];
            float m = siv + smax;
            m = (m >= 0.f) ? m : 0.2f * m;
            float z = 0.f;
            short* prow = &PSb[w][i_loc][0];
#pragma unroll
            for (int k = 0; k < 2; ++k) {
                int jj = k * 128 + lane * 2;
                int ja = idxS[w][jj], jb = idxS[w][jj + 1];
                float ava = adjbuf[r][ja], avb = adjbuf[r][jb];
                float ea = siv + sjS[w][jj];
                float eb = siv + sjS[w][jj + 1];
                ea = (ea >= 0.f) ? ea : 0.2f * ea;
                eb = (eb >= 0.f) ? eb : 0.2f * eb;
                float ca = __expf(ea - m);
                float cb = __expf(eb - m);
                z += ca + cb;
                short2 p;
                p.x = f2bf(ca * ava);
                p.y = f2bf(cb * avb);
                *(short2*)&prow[jj] = p;
            }
#pragma unroll
            for (int off = 32; off >= 1; off >>= 1) z += __shfl_xor(z, off);
            if (lane == 0) invZS[w][i_loc] = 1.0f / z;
        }
        if (s < 3) {
            __syncthreads();   // all waves done reading adjbuf
            const float4* src = (const float4*)(adjb + (size_t)(i0 + (s + 1) * 4) * NN);
            float4* dst = (float4*)adjbuf;
#pragma unroll
            for (int q = 0; q < 8; ++q)
                dst[q * 256 + t] = src[q * 256 + t];
            __syncthreads();
        }
    }
    // MFMA phase: PSb[w] is wave-private -> no barrier needed.
#pragma unroll
    for (int ni = 0; ni < 2; ++ni) {
        float4v acc = {0.f, 0.f, 0.f, 0.f};
#pragma unroll
        for (int ks = 0; ks < 8; ++ks) {
            short8 afr = *(const short8*)&PSb[w][mr][ks * 32 + quad * 8];
            acc = __builtin_amdgcn_mfma_f32_16x16x32_bf16(afr, bfr[ni][ks], acc, 0, 0, 0);
        }
#pragma unroll
        for (int r = 0; r < 4; ++r) {
            int i_loc = quad * 4 + r;
            int d = ni * 16 + mr;
            out[((size_t)(b * NN + i0 + i_loc)) * (HH * HD) + w * HD + d] =
                acc[r] * invZS[w][i_loc];
        }
    }
}

// ---------------------------------------------------------------------------
extern "C" void kernel_launch(void* const* d_in, const int* in_sizes, int n_in,
                              void* d_out, int out_size, void* d_ws, size_t ws_size,
                              hipStream_t stream) {
    const float* h   = (const float*)d_in[0];   // [B,N,DIN]
    const float* adj = (const float*)d_in[1];   // [B,N,N]
    const float* W   = (const float*)d_in[2];   // [H,DIN,HD]
    const float* a   = (const float*)d_in[3];   // [H,2*HD]
    float* out = (float*)d_out;                 // [B,N,H*HD]

    float* si     = (float*)d_ws;                        // BH*NN f32
    float* sjsel  = si + (size_t)BH * NN;                // BH*KSEL
    float* sjmax  = sjsel + (size_t)BH * KSEL;           // BH (pad 16)
    int*   idxsel = (int*)(sjmax + 16);                  // BH*KSEL
    short* Whsel  = (short*)(idxsel + (size_t)BH * KSEL);// BH*HD*KPAD bf16

    select_kernel<<<BH, 1024, 0, stream>>>(h, W, a, si, idxsel, sjsel, sjmax, Whsel);
    attn2_kernel<<<BB * 128, 256, 0, stream>>>(adj, si, idxsel, sjsel, sjmax, Whsel, out);
}

// Round 11
// 128.322 us; speedup vs baseline: 1.2904x; 1.2904x over previous
//
#include <hip/hip_runtime.h>
#include <hip/hip_bf16.h>
#include <cmath>

#define BB 4
#define NN 2048
#define DIN 128
#define HH 4
#define HD 32
#define KSEL 204            // int(0.1 * 2048)
#define BH (BB*HH)
#define KPAD 256            // K padded to 8 MFMA steps of 32
#define KST 264             // PSb row stride (shorts): 132 words -> 2-way banks (free)

typedef __attribute__((ext_vector_type(8))) short short8;
typedef __attribute__((ext_vector_type(4))) short short4v;
typedef __attribute__((ext_vector_type(4))) float float4v;

static __device__ inline short f2bf(float x) {
    __hip_bfloat16 b = __float2bfloat16(x);   // RNE
    return __builtin_bit_cast(short, b);
}

// ---------------------------------------------------------------------------
// K1: s_i = h.(W@a1), s_j = h.(W@a2) (f32-exact). 128 blocks for parallelism.
__global__ __launch_bounds__(256) void s_kernel(const float* __restrict__ h,
                                                const float* __restrict__ W,
                                                const float* __restrict__ a,
                                                float* __restrict__ si, float* __restrict__ sj) {
    int bh = blockIdx.x >> 3, chunk = blockIdx.x & 7;
    int b = bh >> 2, hh = bh & 3;
    __shared__ float w1[128], w2[128];
    int t = threadIdx.x;
    {   // wa = W[hh] @ a-halves, computed in-block
        int f = t & 127, half = t >> 7;
        const float* Wp = W + (size_t)hh * (DIN * HD) + f * HD;
        const float* ap = a + hh * 64 + half * 32;
        float acc = 0.f;
#pragma unroll
        for (int d = 0; d < 32; ++d) acc += Wp[d] * ap[d];
        if (half == 0) w1[f] = acc; else w2[f] = acc;
    }
    __syncthreads();
    int n = chunk * 256 + t;
    const float4* hr = (const float4*)(h + ((size_t)b * NN + n) * DIN);
    float s1 = 0.f, s2 = 0.f;
#pragma unroll 8
    for (int q = 0; q < 32; ++q) {
        float4 x = hr[q];
        s1 += x.x * w1[q*4] + x.y * w1[q*4+1] + x.z * w1[q*4+2] + x.w * w1[q*4+3];
        s2 += x.x * w2[q*4] + x.y * w2[q*4+1] + x.z * w2[q*4+2] + x.w * w2[q*4+3];
    }
    int o = bh * NN + n;
    si[o] = s1; sj[o] = s2;
}

// ---------------------------------------------------------------------------
// K2: select per (b,h), 1024 threads (16 waves):
//  radix-select top-KSEL (register keys, parallel suffix-scan), ordered
//  compaction, then Whsel[bh][d][jj] = bf16( h[sel jj] @ W[hh] ) via MFMA
//  (Wh is ONLY ever needed for the 204 selected rows -> no full wh pass).
__global__ __launch_bounds__(1024) void select_kernel(
        const float* __restrict__ h, const float* __restrict__ W,
        const float* __restrict__ sj,
        int* __restrict__ idxsel, float* __restrict__ sjsel,
        float* __restrict__ sjmax, short* __restrict__ Whsel) {
    int bh = blockIdx.x;
    int b = bh >> 2, hh = bh & 3;
    int t = threadIdx.x, lane = t & 63, w = t >> 6;
    __shared__ float sv[NN];
    __shared__ short WT[32][136];            // WT[d][k] = bf16(W[hh][k][d])
    __shared__ int hist16[16][256];
    __shared__ int binInfo[2];               // [0]=Bsel, [1]=cum_before
    __shared__ int wtot[4];
    __shared__ int wtotg[16], wtote[16], woffg[16], woffe[16];
    __shared__ float wmax[16];
    __shared__ int idxLDS[KSEL];

    for (int e = t; e < 32 * 128; e += 1024) {
        int n = e >> 7, k = e & 127;
        WT[n][k] = f2bf(W[(size_t)hh * (DIN * HD) + k * HD + n]);
    }

    // coalesced sj load; keys in registers
    const float* s = sj + (size_t)bh * NN;
    int j0 = t * 2;
    float2 xx = *(const float2*)(s + j0);
    sv[j0] = xx.x; sv[j0 + 1] = xx.y;
    unsigned u0 = __builtin_bit_cast(unsigned, xx.x);
    unsigned u1 = __builtin_bit_cast(unsigned, xx.y);
    u0 = (u0 & 0x80000000u) ? ~u0 : (u0 | 0x80000000u);
    u1 = (u1 & 0x80000000u) ? ~u1 : (u1 | 0x80000000u);
    float lmax = fmaxf(xx.x, xx.y);
#pragma unroll
    for (int off = 32; off >= 1; off >>= 1) lmax = fmaxf(lmax, __shfl_xor(lmax, off));
    if (lane == 0) wmax[w] = lmax;
    __syncthreads();
    if (t == 0) {
        float m = wmax[0];
#pragma unroll
        for (int i = 1; i < 16; ++i) m = fmaxf(m, wmax[i]);
        sjmax[bh] = m;
    }

    // radix: 4-pass byte histogram, parallel suffix-scan threshold search
    unsigned prefix = 0;
    int need = KSEL;
#pragma unroll
    for (int shift = 24; shift >= 0; shift -= 8) {
        ((int*)hist16)[t] = 0; ((int*)hist16)[t + 1024] = 0;
        ((int*)hist16)[t + 2048] = 0; ((int*)hist16)[t + 3072] = 0;
        __syncthreads();
        unsigned hmask = (shift < 24) ? (0xFFFFFFFFu << (shift + 8)) : 0u;
        if (((u0 ^ prefix) & hmask) == 0) atomicAdd(&hist16[w][(u0 >> shift) & 255], 1);
        if (((u1 ^ prefix) & hmask) == 0) atomicAdd(&hist16[w][(u1 >> shift) & 255], 1);
        __syncthreads();
        int sc = 0, hv = 0, bb = 0;
        if (t < 256) {                 // waves 0..3
            bb = 255 - t;
            hv = 0;
#pragma unroll
            for (int i = 0; i < 16; ++i) hv += hist16[i][bb];
            sc = hv;
#pragma unroll
            for (int off = 1; off < 64; off <<= 1) {
                int u = __shfl_up(sc, off);
                if (lane >= off) sc += u;
            }
            if (lane == 63) wtot[w] = sc;
        }
        __syncthreads();
        if (t < 256) {
            int woffset = 0;
#pragma unroll
            for (int i = 0; i < 4; ++i) woffset += (i < w) ? wtot[i] : 0;
            int incl = sc + woffset;
            int excl = incl - hv;
            if (incl >= need && excl < need) {   // unique thread
                binInfo[0] = bb;
                binInfo[1] = excl;
            }
        }
        __syncthreads();
        prefix |= ((unsigned)binInfo[0]) << shift;
        need -= binInfo[1];
        __syncthreads();
    }
    unsigned T = prefix;
    int n_gt = KSEL - need;        // count of keys strictly > T

    // ordered compaction (thread t owns j0, j0+1)
    int cg = (u0 > T ? 1 : 0) + (u1 > T ? 1 : 0);
    int ce = (u0 == T ? 1 : 0) + (u1 == T ? 1 : 0);
    int sg = cg, se = ce;
#pragma unroll
    for (int off = 1; off < 64; off <<= 1) {
        int ug = __shfl_up(sg, off), ue = __shfl_up(se, off);
        if (lane >= off) { sg += ug; se += ue; }
    }
    if (lane == 63) { wtotg[w] = sg; wtote[w] = se; }
    __syncthreads();
    if (t == 0) {
        int rg = 0, re = 0;
#pragma unroll
        for (int i = 0; i < 16; ++i) {
            woffg[i] = rg; rg += wtotg[i];
            woffe[i] = re; re += wtote[i];
        }
    }
    __syncthreads();
    int pg = woffg[w] + sg - cg;
    int te = woffe[w] + se - ce;
    {
        unsigned kk[2] = {u0, u1};
#pragma unroll
        for (int r = 0; r < 2; ++r) {
            int j = j0 + r;
            if (kk[r] > T) {
                idxsel[bh * KSEL + pg] = j;
                sjsel[bh * KSEL + pg] = sv[j];
                idxLDS[pg] = j;
                pg++;
            } else if (kk[r] == T) {
                if (te < need) {
                    int pos = n_gt + te;
                    idxsel[bh * KSEL + pos] = j;
                    sjsel[bh * KSEL + pos] = sv[j];
                    idxLDS[pos] = j;
                }
                te++;
            }
        }
    }
    __syncthreads();

    // Phase D: Whsel[bh][d][jj] = bf16( h[idxLDS[jj]] @ W[hh] ), tail zero.
    {
        int mr = lane & 15, quad = lane >> 4;
        int jjp = w * 16 + mr;
        bool valid = jjp < KSEL;
        const float* hrow = h + ((size_t)b * NN + (valid ? idxLDS[jjp] : 0)) * DIN + quad * 8;
        float4v acc0 = {0.f, 0.f, 0.f, 0.f};
        float4v acc1 = {0.f, 0.f, 0.f, 0.f};
#pragma unroll
        for (int ks = 0; ks < 4; ++ks) {
            short8 afr;
            if (valid) {
                float4 xa = *(const float4*)(hrow + ks * 32);
                float4 xb = *(const float4*)(hrow + ks * 32 + 4);
                afr[0] = f2bf(xa.x); afr[1] = f2bf(xa.y); afr[2] = f2bf(xa.z); afr[3] = f2bf(xa.w);
                afr[4] = f2bf(xb.x); afr[5] = f2bf(xb.y); afr[6] = f2bf(xb.z); afr[7] = f2bf(xb.w);
            } else {
                afr = (short8){0, 0, 0, 0, 0, 0, 0, 0};
            }
            short8 b0 = *(const short8*)&WT[mr][ks * 32 + quad * 8];
            short8 b1 = *(const short8*)&WT[16 + mr][ks * 32 + quad * 8];
            acc0 = __builtin_amdgcn_mfma_f32_16x16x32_bf16(afr, b0, acc0, 0, 0, 0);
            acc1 = __builtin_amdgcn_mfma_f32_16x16x32_bf16(afr, b1, acc1, 0, 0, 0);
        }
        short4v o0, o1;
#pragma unroll
        for (int r = 0; r < 4; ++r) { o0[r] = f2bf(acc0[r]); o1[r] = f2bf(acc1[r]); }
        size_t base = (size_t)bh * HD * KPAD;
        int jjs = w * 16 + quad * 4;
        *(short4v*)&Whsel[base + (size_t)mr * KPAD + jjs] = o0;
        *(short4v*)&Whsel[base + (size_t)(16 + mr) * KPAD + jjs] = o1;
    }
}

// ---------------------------------------------------------------------------
// K3: FUSED attention. Block = (b, 16 rows, 4 heads-as-waves), grid 512.
// 4 stages: 4 dense adj rows -> LDS (shared by all heads); wave w computes
// head w's P rows into its PRIVATE PSb[w]; barriers only guard adjbuf.
// Then wave w MFMAs PSb[w] @ bfr (registers) -> out * invZ. ~75 KB LDS.
__global__ __launch_bounds__(256) void attn2_kernel(
        const float* __restrict__ adj, const float* __restrict__ si,
        const int* __restrict__ idxsel, const float* __restrict__ sjsel,
        const float* __restrict__ sjmax, const short* __restrict__ Whsel,
        float* __restrict__ out) {
    int b = blockIdx.x >> 7;        // 4
    int tile = blockIdx.x & 127;    // 128 tiles of 16 rows
    __shared__ float adjbuf[4][NN];          // 32 KB
    __shared__ short PSb[HH][16][KST];       // 33 KB, per-head private
    __shared__ int   idxS[HH][KPAD];         // 4 KB
    __shared__ float sjS[HH][KPAD];          // 4 KB
    __shared__ float invZS[HH][16];
    __shared__ float smaxS[HH];
    int t = threadIdx.x, w = t >> 6, lane = t & 63;
    int mr = lane & 15, quad = lane >> 4;

    // padded per-head tables
    for (int e = t; e < HH * KPAD; e += 256) {
        int hh = e >> 8, jj = e & 255;
        bool v = jj < KSEL;
        idxS[hh][jj] = v ? idxsel[(b * HH + hh) * KSEL + jj] : 0;
        sjS[hh][jj]  = v ? sjsel[(b * HH + hh) * KSEL + jj] : -1e30f;
    }
    if (t < HH) smaxS[t] = sjmax[b * HH + t];

    // B-fragments for head w (registers, reused all block)
    short8 bfr[2][8];
    {
        const short* wp = Whsel + (size_t)((b * HH + w) * HD) * KPAD;
#pragma unroll
        for (int ni = 0; ni < 2; ++ni)
#pragma unroll
            for (int ks = 0; ks < 8; ++ks)
                bfr[ni][ks] = *(const short8*)(wp + (size_t)(ni * 16 + mr) * KPAD + ks * 32 + quad * 8);
    }

    int i0 = tile * 16;
    const float* adjb = adj + (size_t)b * NN * NN;
    // stage 0: 4 dense adj rows
    {
        const float4* src = (const float4*)(adjb + (size_t)i0 * NN);
        float4* dst = (float4*)adjbuf;
#pragma unroll
        for (int q = 0; q < 8; ++q)
            dst[q * 256 + t] = src[q * 256 + t];
    }
    __syncthreads();

    int bh = b * HH + w;
    float smax = smaxS[w];
    for (int s = 0; s < 4; ++s) {
#pragma unroll
        for (int r = 0; r < 4; ++r) {
            int i_loc = s * 4 + r;
            int i = i0 + i_loc;
            float siv = si[(size_t)bh * NN + i];
            float m = siv + smax;
            m = (m >= 0.f) ? m : 0.2f * m;
            float z = 0.f;
            short* prow = &PSb[w][i_loc][0];
#pragma unroll
            for (int k = 0; k < 2; ++k) {
                int jj = k * 128 + lane * 2;
                int ja = idxS[w][jj], jb = idxS[w][jj + 1];
                float ava = adjbuf[r][ja], avb = adjbuf[r][jb];
                float ea = siv + sjS[w][jj];
                float eb = siv + sjS[w][jj + 1];
                ea = (ea >= 0.f) ? ea : 0.2f * ea;
                eb = (eb >= 0.f) ? eb : 0.2f * eb;
                float ca = __expf(ea - m);
                float cb = __expf(eb - m);
                z += ca + cb;
                short2 p;
                p.x = f2bf(ca * ava);
                p.y = f2bf(cb * avb);
                *(short2*)&prow[jj] = p;
            }
#pragma unroll
            for (int off = 32; off >= 1; off >>= 1) z += __shfl_xor(z, off);
            if (lane == 0) invZS[w][i_loc] = 1.0f / z;
        }
        if (s < 3) {
            __syncthreads();   // all waves done reading adjbuf
            const float4* src = (const float4*)(adjb + (size_t)(i0 + (s + 1) * 4) * NN);
            float4* dst = (float4*)adjbuf;
#pragma unroll
            for (int q = 0; q < 8; ++q)
                dst[q * 256 + t] = src[q * 256 + t];
            __syncthreads();
        }
    }
    // MFMA phase: PSb[w] is wave-private -> no barrier needed.
#pragma unroll
    for (int ni = 0; ni < 2; ++ni) {
        float4v acc = {0.f, 0.f, 0.f, 0.f};
#pragma unroll
        for (int ks = 0; ks < 8; ++ks) {
            short8 afr = *(const short8*)&PSb[w][mr][ks * 32 + quad * 8];
            acc = __builtin_amdgcn_mfma_f32_16x16x32_bf16(afr, bfr[ni][ks], acc, 0, 0, 0);
        }
#pragma unroll
        for (int r = 0; r < 4; ++r) {
            int i_loc = quad * 4 + r;
            int d = ni * 16 + mr;
            out[((size_t)(b * NN + i0 + i_loc)) * (HH * HD) + w * HD + d] =
                acc[r] * invZS[w][i_loc];
        }
    }
}

// ---------------------------------------------------------------------------
extern "C" void kernel_launch(void* const* d_in, const int* in_sizes, int n_in,
                              void* d_out, int out_size, void* d_ws, size_t ws_size,
                              hipStream_t stream) {
    const float* h   = (const float*)d_in[0];   // [B,N,DIN]
    const float* adj = (const float*)d_in[1];   // [B,N,N]
    const float* W   = (const float*)d_in[2];   // [H,DIN,HD]
    const float* a   = (const float*)d_in[3];   // [H,2*HD]
    float* out = (float*)d_out;                 // [B,N,H*HD]

    float* si     = (float*)d_ws;                        // BH*NN f32
    float* sj     = si + (size_t)BH * NN;                // BH*NN
    float* sjsel  = sj + (size_t)BH * NN;                // BH*KSEL
    float* sjmax  = sjsel + (size_t)BH * KSEL;           // BH (pad 16)
    int*   idxsel = (int*)(sjmax + 16);                  // BH*KSEL
    short* Whsel  = (short*)(idxsel + (size_t)BH * KSEL);// BH*HD*KPAD bf16

    s_kernel<<<BH * 8, 256, 0, stream>>>(h, W, a, si, sj);
    select_kernel<<<BH, 1024, 0, stream>>>(h, W, sj, idxsel, sjsel, sjmax, Whsel);
    attn2_kernel<<<BB * 128, 256, 0, stream>>>(adj, si, idxsel, sjsel, sjmax, Whsel, out);
}